// Round 6
// baseline (148.895 us; speedup 1.0000x reference)
//
#include <hip/hip_runtime.h>
#include <hip/hip_bf16.h>
#include <cstdint>
#include <cstddef>

#define BATCH   8192
#define NSAMP   8192
#define DIM     512
#define NCLASS  50000

typedef __attribute__((ext_vector_type(8))) short bf16x8;
typedef __attribute__((ext_vector_type(4))) float f32x4;

// -log(expected_count(c)) for the log-uniform sampler, in double to match the
// numpy reference (f32 log(c+2)-log(c+1) catastrophically cancels at large c).
__device__ __forceinline__ float neg_log_expected(int c) {
    double p = log1p(1.0 / (double)(c + 1)) / log((double)(NCLASS + 1));
    double e = -expm1((double)NSAMP * log1p(-p));
    return (float)(-log(e));
}

__device__ __forceinline__ unsigned short f2bf(float f) {
    __hip_bfloat16 h = __float2bfloat16(f);
    return *reinterpret_cast<unsigned short*>(&h);
}

__device__ __forceinline__ void gload_lds16(const void* g, void* l) {
    __builtin_amdgcn_global_load_lds(
        (const __attribute__((address_space(1))) void*)g,
        (__attribute__((address_space(3))) void*)l, 16, 0, 0);
}

// ---- kernel 1: fused inputs f32->bf16 + true-logit + row_sum seed ----------
__global__ void k_fused(const float* __restrict__ inputs, const int* __restrict__ labels,
                        const float* __restrict__ W, const float* __restrict__ bias,
                        __hip_bfloat16* __restrict__ Abf,
                        float* __restrict__ true_logit, float* __restrict__ row_sum) {
    int row = blockIdx.x;
    int t   = threadIdx.x;                       // 0..127
    float4 v = reinterpret_cast<const float4*>(inputs + (size_t)row * DIM)[t];
    ushort4 u;
    u.x = f2bf(v.x); u.y = f2bf(v.y); u.z = f2bf(v.z); u.w = f2bf(v.w);
    reinterpret_cast<ushort4*>(Abf + (size_t)row * DIM)[t] = u;

    int lbl = labels[row];
    float4 w = reinterpret_cast<const float4*>(W + (size_t)lbl * DIM)[t];
    float dot = v.x * w.x + v.y * w.y + v.z * w.z + v.w * w.w;
    #pragma unroll
    for (int off = 32; off; off >>= 1) dot += __shfl_down(dot, off, 64);
    __shared__ float red[2];
    if ((t & 63) == 0) red[t >> 6] = dot;
    __syncthreads();
    if (t == 0) {
        float tl = red[0] + red[1] + bias[lbl] + neg_log_expected(lbl);
        true_logit[row] = tl;
        row_sum[row]    = __expf(tl);
    }
}

// ---- kernel 2: gather kernel[sampled] -> bf16 B; adj[s] = bias - log(expected)
__global__ void k_gather(const float* __restrict__ W, const float* __restrict__ bias,
                         const int* __restrict__ sampled,
                         __hip_bfloat16* __restrict__ Bbf, float* __restrict__ adj) {
    int s   = blockIdx.x;
    int idx = sampled[s];
    float4 v = reinterpret_cast<const float4*>(W + (size_t)idx * DIM)[threadIdx.x];
    ushort4 u;
    u.x = f2bf(v.x); u.y = f2bf(v.y); u.z = f2bf(v.z); u.w = f2bf(v.w);
    reinterpret_cast<ushort4*>(Bbf + (size_t)s * DIM)[threadIdx.x] = u;
    if (threadIdx.x == 0) adj[s] = bias[idx] + neg_log_expected(idx);
}

// ---- kernel 3: 8192x8192x512 bf16 GEMM, persistent flat pipeline ------------
// Round-5: grid 512 (2 blocks/CU). Each block = one 128-row band x 8 col-tiles
// processed by ONE flat 128-step pipeline (BK=32, 4 LDS buffers, lead-3,
// uniform vmcnt(8)) that crosses tile boundaries seamlessly: one pipeline fill
// per BLOCK (was per TILE = 8x), no inter-tile drains, epilogue overlapped
// with in-flight staging (its barrier waits lgkmcnt only, NOT vmcnt).
// xcd=rb&7: A band XCD-L2-resident; the 8 same-XCD blocks walk the same
// col-sequence so each B panel is shared in L2. Inner step / swizzle /
// epilogue = round-1's proven code (0 bank conflicts, absmax 0.0625).

#define BARRIER()  asm volatile("s_barrier" ::: "memory")
#define LBARRIER() asm volatile("s_waitcnt lgkmcnt(0)\n\ts_barrier" ::: "memory")
#define VMCNT(n)   asm volatile("s_waitcnt vmcnt(" #n ")" ::: "memory")

__global__ __launch_bounds__(256, 2) void k_gemm(
    const __hip_bfloat16* __restrict__ A, const __hip_bfloat16* __restrict__ B,
    const float* __restrict__ adj, const int* __restrict__ labels,
    const int* __restrict__ sampled, float* __restrict__ row_sum) {
    __shared__ alignas(16) __hip_bfloat16 Asm[4][128 * 32];   // 32 KiB
    __shared__ alignas(16) __hip_bfloat16 Bsm[4][128 * 32];   // 32 KiB
    __shared__ float tsum[2][128];                            // 1 KiB

    const int tid  = threadIdx.x;
    const int wave = tid >> 6;
    const int lane = tid & 63;
    const int wr   = wave >> 1;
    const int wc   = wave & 1;

    // bid -> (rb, cg): xcd = bid&7 == rb&7 (A-band locality); 8 same-XCD
    // blocks share cg's col sequence (B L2 reuse). Bijective.
    const int bid  = blockIdx.x;
    const int xcd  = bid & 7;
    const int idx  = bid >> 3;                 // 0..63
    const int rb   = (idx & 7) * 8 + xcd;      // 0..63
    const int cg   = idx >> 3;                 // 0..7
    const int brow = rb * 128;

    // staging: lane covers row (lane>>2) of a 16-row chunk, phys granule
    // lane&3; fetch logical granule (lane&3)^f(row), f(row)=(row>>1)&3
    const int srow = lane >> 2;
    const int sg   = (lane & 3) ^ ((lane >> 3) & 3);
    // fragment read: row = ...+rsel, phys granule = (lane>>4) ^ f(row)
    const int rsel = lane & 15;
    const int koff = ((lane >> 4) ^ ((lane >> 1) & 3)) * 8;

    f32x4 acc[4][4];
    #pragma unroll
    for (int m = 0; m < 4; ++m)
        #pragma unroll
        for (int n = 0; n < 4; ++n)
            acc[m][n] = (f32x4){0.f, 0.f, 0.f, 0.f};

    // global step g in [0,128): tile t = g>>4 (col = cg*8+t), kt = g&15,
    // buffer = g&3.
    auto stage = [&](int g) {
        const int buf = g & 3, t = g >> 4, kt = g & 15;
        const int bcol = (cg * 8 + t) * 128;
        #pragma unroll
        for (int i = 0; i < 2; ++i) {
            const __hip_bfloat16* gA =
                A + (size_t)(brow + wave * 32 + i * 16 + srow) * DIM + kt * 32 + sg * 8;
            gload_lds16(gA, &Asm[buf][(wave * 32 + i * 16) * 32]);
            const __hip_bfloat16* gB =
                B + (size_t)(bcol + wave * 32 + i * 16 + srow) * DIM + kt * 32 + sg * 8;
            gload_lds16(gB, &Bsm[buf][(wave * 32 + i * 16) * 32]);
        }
    };

    auto body = [&](int buf) {
        bf16x8 a[4], b[4];
        #pragma unroll
        for (int m = 0; m < 4; ++m)
            a[m] = *reinterpret_cast<const bf16x8*>(
                &Asm[buf][(wr * 64 + m * 16 + rsel) * 32 + koff]);
        #pragma unroll
        for (int n = 0; n < 4; ++n)
            b[n] = *reinterpret_cast<const bf16x8*>(
                &Bsm[buf][(wc * 64 + n * 16 + rsel) * 32 + koff]);
        #pragma unroll
        for (int m = 0; m < 4; ++m)
            #pragma unroll
            for (int n = 0; n < 4; ++n)
                acc[m][n] = __builtin_amdgcn_mfma_f32_16x16x32_bf16(a[m], b[n], acc[m][n], 0, 0, 0);
    };

    // epilogue for tile t: exp/mask/row-sum; waits lgkm only (staging loads
    // for the next tile stay in flight). Resets acc.
    auto epi = [&](int t) {
        const int bcol = (cg * 8 + t) * 128;
        int sv[4]; float aadj[4];
        #pragma unroll
        for (int n = 0; n < 4; ++n) {
            int col = bcol + wc * 64 + n * 16 + rsel;
            aadj[n] = adj[col];
            sv[n]   = sampled[col];
        }
        #pragma unroll
        for (int m = 0; m < 4; ++m) {
            #pragma unroll
            for (int r = 0; r < 4; ++r) {
                int lr  = wr * 64 + m * 16 + (lane >> 4) * 4 + r;
                int lbl = labels[brow + lr];
                float part = 0.f;
                #pragma unroll
                for (int n = 0; n < 4; ++n) {
                    float logit = acc[m][n][r] + aadj[n];
                    part += (sv[n] == lbl) ? 0.f : __expf(logit);
                }
                part += __shfl_xor(part, 1, 16);
                part += __shfl_xor(part, 2, 16);
                part += __shfl_xor(part, 4, 16);
                part += __shfl_xor(part, 8, 16);
                if (rsel == 0) tsum[wc][lr] = part;
            }
        }
        LBARRIER();
        if (tid < 128)
            atomicAdd(&row_sum[brow + tid], tsum[0][tid] + tsum[1][tid]);
        #pragma unroll
        for (int m = 0; m < 4; ++m)
            #pragma unroll
            for (int n = 0; n < 4; ++n)
                acc[m][n] = (f32x4){0.f, 0.f, 0.f, 0.f};
    };

    // prologue: fill 3 of 4 buffers (lead = 3 steps)
    stage(0); stage(1); stage(2);

    #pragma unroll 1
    for (int g = 0; g < 126; ++g) {
        VMCNT(8);                 // stage g complete ({g,g+1,g+2} outstanding)
        BARRIER();                // all waves past step g-1 reads
        const int buf = g & 3;
        if (g + 3 < 128) stage(g + 3);   // targets buffer (g-1)&3 — free now
        body(buf);
        if ((g & 15) == 15) epi(g >> 4); // tiles 0..6 (g=15..111)
    }
    // peeled drain: g = 126, 127
    VMCNT(4); BARRIER(); body(2);
    VMCNT(0); BARRIER(); body(3);
    epi(7);
}

// ---- kernel 4: loss = log(row_sum) - true_logit -----------------------------
__global__ void k_final(const float* __restrict__ row_sum,
                        const float* __restrict__ true_logit,
                        float* __restrict__ loss) {
    int i = blockIdx.x * blockDim.x + threadIdx.x;
    loss[i] = logf(row_sum[i]) - true_logit[i];
}

extern "C" void kernel_launch(void* const* d_in, const int* in_sizes, int n_in,
                              void* d_out, int out_size, void* d_ws, size_t ws_size,
                              hipStream_t stream) {
    const float* inputs  = (const float*)d_in[0];
    const int*   labels  = (const int*)d_in[1];
    const float* W       = (const float*)d_in[2];
    const float* bias    = (const float*)d_in[3];
    const int*   sampled = (const int*)d_in[4];
    float*       loss    = (float*)d_out;

    char* ws = (char*)d_ws;
    __hip_bfloat16* Abf = (__hip_bfloat16*)ws;                                  // 8 MiB
    __hip_bfloat16* Bbf = (__hip_bfloat16*)(ws + (size_t)BATCH * DIM * 2);      // 8 MiB
    float* adj        = (float*)(ws + (size_t)(BATCH + NSAMP) * DIM * 2);       // 32 KiB
    float* true_logit = adj + NSAMP;                                            // 32 KiB
    float* row_sum    = true_logit + BATCH;                                     // 32 KiB

    hipLaunchKernelGGL(k_fused, dim3(BATCH), dim3(128), 0, stream,
                       inputs, labels, W, bias, Abf, true_logit, row_sum);
    hipLaunchKernelGGL(k_gather, dim3(NSAMP), dim3(128), 0, stream,
                       W, bias, sampled, Bbf, adj);
    hipLaunchKernelGGL(k_gemm, dim3(512), dim3(256), 0, stream,
                       Abf, Bbf, adj, labels, sampled, row_sum);
    hipLaunchKernelGGL(k_final, dim3(BATCH / 256), dim3(256), 0, stream,
                       row_sum, true_logit, loss);
}

// Round 7
// 124.983 us; speedup vs baseline: 1.1913x; 1.1913x over previous
//
#include <hip/hip_runtime.h>
#include <hip/hip_bf16.h>
#include <cstdint>
#include <cstddef>

#define BATCH   8192
#define NSAMP   8192
#define DIM     512
#define NCLASS  50000

typedef __attribute__((ext_vector_type(8))) short bf16x8;
typedef __attribute__((ext_vector_type(4))) float f32x4;

// -log(expected_count(c)) for the log-uniform sampler, in double to match the
// numpy reference (f32 log(c+2)-log(c+1) catastrophically cancels at large c).
__device__ __forceinline__ float neg_log_expected(int c) {
    double p = log1p(1.0 / (double)(c + 1)) / log((double)(NCLASS + 1));
    double e = -expm1((double)NSAMP * log1p(-p));
    return (float)(-log(e));
}

__device__ __forceinline__ unsigned short f2bf(float f) {
    __hip_bfloat16 h = __float2bfloat16(f);
    return *reinterpret_cast<unsigned short*>(&h);
}

__device__ __forceinline__ void gload_lds16(const void* g, void* l) {
    __builtin_amdgcn_global_load_lds(
        (const __attribute__((address_space(1))) void*)g,
        (__attribute__((address_space(3))) void*)l, 16, 0, 0);
}

// ---- kernel 1: fused inputs f32->bf16 + true-logit + row_sum seed ----------
__global__ void k_fused(const float* __restrict__ inputs, const int* __restrict__ labels,
                        const float* __restrict__ W, const float* __restrict__ bias,
                        __hip_bfloat16* __restrict__ Abf,
                        float* __restrict__ true_logit, float* __restrict__ row_sum) {
    int row = blockIdx.x;
    int t   = threadIdx.x;                       // 0..127
    float4 v = reinterpret_cast<const float4*>(inputs + (size_t)row * DIM)[t];
    ushort4 u;
    u.x = f2bf(v.x); u.y = f2bf(v.y); u.z = f2bf(v.z); u.w = f2bf(v.w);
    reinterpret_cast<ushort4*>(Abf + (size_t)row * DIM)[t] = u;

    int lbl = labels[row];
    float4 w = reinterpret_cast<const float4*>(W + (size_t)lbl * DIM)[t];
    float dot = v.x * w.x + v.y * w.y + v.z * w.z + v.w * w.w;
    #pragma unroll
    for (int off = 32; off; off >>= 1) dot += __shfl_down(dot, off, 64);
    __shared__ float red[2];
    if ((t & 63) == 0) red[t >> 6] = dot;
    __syncthreads();
    if (t == 0) {
        float tl = red[0] + red[1] + bias[lbl] + neg_log_expected(lbl);
        true_logit[row] = tl;
        row_sum[row]    = __expf(tl);
    }
}

// ---- kernel 2: gather kernel[sampled] -> bf16 B; adj[s] = bias - log(expected)
__global__ void k_gather(const float* __restrict__ W, const float* __restrict__ bias,
                         const int* __restrict__ sampled,
                         __hip_bfloat16* __restrict__ Bbf, float* __restrict__ adj) {
    int s   = blockIdx.x;
    int idx = sampled[s];
    float4 v = reinterpret_cast<const float4*>(W + (size_t)idx * DIM)[threadIdx.x];
    ushort4 u;
    u.x = f2bf(v.x); u.y = f2bf(v.y); u.z = f2bf(v.z); u.w = f2bf(v.w);
    reinterpret_cast<ushort4*>(Bbf + (size_t)s * DIM)[threadIdx.x] = u;
    if (threadIdx.x == 0) adj[s] = bias[idx] + neg_log_expected(idx);
}

// ---- kernel 3: 8192x8192x512 bf16 GEMM, residency-first --------------------
// Round-6 theory: all pipes <=35% busy; the limiter is latency-hiding capacity
// (resident waves). Fix: m97's measured-cheapest step (2-buffer, stage ->
// ds_read -> MFMA -> __syncthreads; the sync's vmcnt(0) drain is priced into
// its 736cy/step and makes the epilogue vmem-safe) at BK=32 -> 33KB LDS ->
// 4 RESIDENT BLOCKS/CU (16 waves, 2x round 5). Persistent over 4 col-tiles
// (64 flat steps: one prologue, fixed cost ~9%). XCD raster: 1024 blocks =
// 8 XCD x (8 row-bands x 16 col-groups); per-XCD set ~3MB <= 4MB L2.
// Granule swizzle + epilogue: proven (0 conflicts, absmax 0.0625).
__global__ __launch_bounds__(256, 4) void k_gemm(
    const __hip_bfloat16* __restrict__ A, const __hip_bfloat16* __restrict__ B,
    const float* __restrict__ adj, const int* __restrict__ labels,
    const int* __restrict__ sampled, float* __restrict__ row_sum) {
    __shared__ alignas(16) __hip_bfloat16 Asm[2][128 * 32];   // 16 KiB
    __shared__ alignas(16) __hip_bfloat16 Bsm[2][128 * 32];   // 16 KiB
    __shared__ float tsum[2][128];                            // 1 KiB

    const int tid  = threadIdx.x;
    const int wave = tid >> 6;
    const int lane = tid & 63;
    const int wr   = wave >> 1;
    const int wc   = wave & 1;

    // bid -> xcd = bid&7 (round-robin dispatch heuristic), u = bid>>3:
    // row-band rb = xcd*8 + (u&7)  (8 bands/XCD: 1MB A, XCD-L2-resident)
    // col-group   = u>>3 (0..15), 4 col-tiles each. Bijective, 1024 blocks.
    const int bid  = blockIdx.x;
    const int xcd  = bid & 7;
    const int u    = bid >> 3;                 // 0..127
    const int rb   = xcd * 8 + (u & 7);        // 0..63
    const int cgrp = u >> 3;                   // 0..15
    const int brow = rb * 128;

    // staging: lane covers row (lane>>2) of a 16-row chunk, phys granule
    // lane&3; fetch logical granule (lane&3)^f(row), f(row)=(row>>1)&3
    const int srow = lane >> 2;
    const int sg   = (lane & 3) ^ ((lane >> 3) & 3);
    // fragment read: row = ...+rsel, phys granule = (lane>>4) ^ f(row)
    const int rsel = lane & 15;
    const int koff = ((lane >> 4) ^ ((lane >> 1) & 3)) * 8;

    f32x4 acc[4][4];
    #pragma unroll
    for (int m = 0; m < 4; ++m)
        #pragma unroll
        for (int n = 0; n < 4; ++n)
            acc[m][n] = (f32x4){0.f, 0.f, 0.f, 0.f};

    // flat step g in [0,64): tile t = g>>4 (col = cgrp*4+t), kt = g&15,
    // buffer = g&1.
    auto stage = [&](int g) {
        const int buf = g & 1, t = g >> 4, kt = g & 15;
        const int bcol = (cgrp * 4 + t) * 128;
        #pragma unroll
        for (int i = 0; i < 2; ++i) {
            const __hip_bfloat16* gA =
                A + (size_t)(brow + wave * 32 + i * 16 + srow) * DIM + kt * 32 + sg * 8;
            gload_lds16(gA, &Asm[buf][(wave * 32 + i * 16) * 32]);
            const __hip_bfloat16* gB =
                B + (size_t)(bcol + wave * 32 + i * 16 + srow) * DIM + kt * 32 + sg * 8;
            gload_lds16(gB, &Bsm[buf][(wave * 32 + i * 16) * 32]);
        }
    };

    auto body = [&](int buf) {
        bf16x8 a[4], b[4];
        #pragma unroll
        for (int m = 0; m < 4; ++m)
            a[m] = *reinterpret_cast<const bf16x8*>(
                &Asm[buf][(wr * 64 + m * 16 + rsel) * 32 + koff]);
        #pragma unroll
        for (int n = 0; n < 4; ++n)
            b[n] = *reinterpret_cast<const bf16x8*>(
                &Bsm[buf][(wc * 64 + n * 16 + rsel) * 32 + koff]);
        #pragma unroll
        for (int m = 0; m < 4; ++m)
            #pragma unroll
            for (int n = 0; n < 4; ++n)
                acc[m][n] = __builtin_amdgcn_mfma_f32_16x16x32_bf16(a[m], b[n], acc[m][n], 0, 0, 0);
    };

    // epilogue for tile t: exp/mask/row-sum; vmcnt is drained every step by
    // __syncthreads, so its global loads can't corrupt any staging ledger.
    auto epi = [&](int t) {
        const int bcol = (cgrp * 4 + t) * 128;
        int sv[4]; float aadj[4];
        #pragma unroll
        for (int n = 0; n < 4; ++n) {
            int col = bcol + wc * 64 + n * 16 + rsel;
            aadj[n] = adj[col];
            sv[n]   = sampled[col];
        }
        #pragma unroll
        for (int m = 0; m < 4; ++m) {
            #pragma unroll
            for (int r = 0; r < 4; ++r) {
                int lr  = wr * 64 + m * 16 + (lane >> 4) * 4 + r;
                int lbl = labels[brow + lr];
                float part = 0.f;
                #pragma unroll
                for (int n = 0; n < 4; ++n) {
                    float logit = acc[m][n][r] + aadj[n];
                    part += (sv[n] == lbl) ? 0.f : __expf(logit);
                }
                part += __shfl_xor(part, 1, 16);
                part += __shfl_xor(part, 2, 16);
                part += __shfl_xor(part, 4, 16);
                part += __shfl_xor(part, 8, 16);
                if (rsel == 0) tsum[wc][lr] = part;
            }
        }
        __syncthreads();
        if (tid < 128)
            atomicAdd(&row_sum[brow + tid], tsum[0][tid] + tsum[1][tid]);
        #pragma unroll
        for (int m = 0; m < 4; ++m)
            #pragma unroll
            for (int n = 0; n < 4; ++n)
                acc[m][n] = (f32x4){0.f, 0.f, 0.f, 0.f};
    };

    stage(0);
    __syncthreads();

    #pragma unroll 1
    for (int g = 0; g < 64; ++g) {
        if (g + 1 < 64) stage(g + 1);     // into buf^1 (safe: prior reads done)
        body(g & 1);
        if ((g & 15) == 15) epi(g >> 4);
        __syncthreads();                  // drains vmcnt: stage(g+1) ready
    }
}

// ---- kernel 4: loss = log(row_sum) - true_logit -----------------------------
__global__ void k_final(const float* __restrict__ row_sum,
                        const float* __restrict__ true_logit,
                        float* __restrict__ loss) {
    int i = blockIdx.x * blockDim.x + threadIdx.x;
    loss[i] = logf(row_sum[i]) - true_logit[i];
}

extern "C" void kernel_launch(void* const* d_in, const int* in_sizes, int n_in,
                              void* d_out, int out_size, void* d_ws, size_t ws_size,
                              hipStream_t stream) {
    const float* inputs  = (const float*)d_in[0];
    const int*   labels  = (const int*)d_in[1];
    const float* W       = (const float*)d_in[2];
    const float* bias    = (const float*)d_in[3];
    const int*   sampled = (const int*)d_in[4];
    float*       loss    = (float*)d_out;

    char* ws = (char*)d_ws;
    __hip_bfloat16* Abf = (__hip_bfloat16*)ws;                                  // 8 MiB
    __hip_bfloat16* Bbf = (__hip_bfloat16*)(ws + (size_t)BATCH * DIM * 2);      // 8 MiB
    float* adj        = (float*)(ws + (size_t)(BATCH + NSAMP) * DIM * 2);       // 32 KiB
    float* true_logit = adj + NSAMP;                                            // 32 KiB
    float* row_sum    = true_logit + BATCH;                                     // 32 KiB

    hipLaunchKernelGGL(k_fused, dim3(BATCH), dim3(128), 0, stream,
                       inputs, labels, W, bias, Abf, true_logit, row_sum);
    hipLaunchKernelGGL(k_gather, dim3(NSAMP), dim3(128), 0, stream,
                       W, bias, sampled, Bbf, adj);
    hipLaunchKernelGGL(k_gemm, dim3(1024), dim3(256), 0, stream,
                       Abf, Bbf, adj, labels, sampled, row_sum);
    hipLaunchKernelGGL(k_final, dim3(BATCH / 256), dim3(256), 0, stream,
                       row_sum, true_logit, loss);
}